// Round 2
// baseline (1034.395 us; speedup 1.0000x reference)
//
#include <hip/hip_runtime.h>
#include <stdint.h>

// Problem constants
#define N_ROWS 8192
#define D_DIM  1024
#define M_CENT 20000
#define M_PAD  20224          // 79 * 256
#define M_TILES 79            // 256-wide center tiles
#define Y_DIM  256
#define BM 64                 // rows of X per block
#define BN 256                // centers per M-iteration (wave tile 64x64)
#define BK 64                 // K-chunk of D
#define NCHUNK 16             // D_DIM / BK
#define MSPLIT 8
#define TILES_PER_SPLIT 10    // ceil(79/8)
#define LDSP_STRIDE 264       // 256 + 8 pad: 33 16B-slots/row ≡ 1 mod 8 -> conflict-free

typedef __attribute__((ext_vector_type(4))) float  f32x4;
typedef __attribute__((ext_vector_type(8))) __bf16 bf16x8;

__device__ __forceinline__ unsigned short f2bf(float f) {
    union { float f; unsigned u; } v; v.f = f;
    unsigned u = v.u;
    u += 0x7FFFu + ((u >> 16) & 1u);   // RNE
    return (unsigned short)(u >> 16);
}

// async global->LDS, 16B per lane. LDS dest must be wave-uniform base + lane*16.
__device__ __forceinline__ void gll16(void* lds, const void* g) {
    __builtin_amdgcn_global_load_lds(
        (const __attribute__((address_space(1))) void*)g,
        (__attribute__((address_space(3))) void*)lds, 16, 0, 0);
}

// cast fp32 rows -> bf16, compute fp32 row sum-of-squares; pad rows -> zeros
__global__ void cast_rows_kernel(const float* __restrict__ src,
                                 unsigned short* __restrict__ dst,
                                 float* __restrict__ sq, int nrows_valid) {
    int row = blockIdx.x;
    int t = threadIdx.x;  // 256 threads, 4 floats each = 1024 = D_DIM
    float s = 0.f;
    if (row < nrows_valid) {
        float4 v = ((const float4*)(src + (size_t)row * D_DIM))[t];
        s = v.x * v.x + v.y * v.y + v.z * v.z + v.w * v.w;
        ushort4 o;
        o.x = f2bf(v.x); o.y = f2bf(v.y); o.z = f2bf(v.z); o.w = f2bf(v.w);
        ((ushort4*)(dst + (size_t)row * D_DIM))[t] = o;
    } else {
        ((ushort4*)(dst + (size_t)row * D_DIM))[t] = make_ushort4(0, 0, 0, 0);
    }
    __shared__ float red[4];
    for (int off = 32; off; off >>= 1) s += __shfl_down(s, off, 64);
    if ((t & 63) == 0) red[t >> 6] = s;
    __syncthreads();
    if (t == 0) sq[row] = red[0] + red[1] + red[2] + red[3];
}

// W [M][Y] fp32 -> WT [Y][M_PAD] bf16, pad rows (centers >= M_CENT) -> 0
__global__ void cast_wT_kernel(const float* __restrict__ w,
                               unsigned short* __restrict__ wT) {
    __shared__ float tile[32][33];
    int k0 = blockIdx.x * 32;   // center dim
    int y0 = blockIdx.y * 32;   // Y dim
    int tx = threadIdx.x & 31;
    int ty = threadIdx.x >> 5;  // 0..7
    #pragma unroll
    for (int i = 0; i < 4; ++i) {
        int k = k0 + ty + i * 8;
        float v = (k < M_CENT) ? w[(size_t)k * Y_DIM + y0 + tx] : 0.f;
        tile[tx][ty + i * 8] = v;     // tile[y_local][k_local]
    }
    __syncthreads();
    #pragma unroll
    for (int i = 0; i < 4; ++i) {
        int yl = ty + i * 8;
        wT[(size_t)(y0 + yl) * M_PAD + k0 + tx] = f2bf(tile[yl][tx]);
    }
}

// ---------------------------------------------------------------------------
// R4: R3's (correctness-verified) dataflow + two fixes from the R3 post-mortem:
//  1. Counted-vmcnt RAW-barrier pipeline (T3+T4).  __syncthreads drains
//     vmcnt(0) at every barrier, exposing the full load time each chunk (the
//     m97 ceiling).  Now: per chunk
//        s_waitcnt vmcnt(8)   <- waits ONLY my 2 X-stage gll16 ops;
//                                the 8 in-flight Bf loads stay outstanding
//        s_barrier            <- raw, no drain
//        STAGE_X(next) ; sched_barrier ; LOAD_B(next) ; sched_barrier
//        ds_read A-frags ; compiler-inserted lgkmcnt + vmcnt(10) ; 32 MFMA
//     Phase-2->3 barrier is lgkmcnt(0)-only, so the next tile's chunk-0
//     prefetch stays in flight across Phases 2-3.  vmcnt never drains to 0
//     in the main loop.
//     Hazard audit: stage into buf[par^1] is after the barrier; all waves'
//     reads of buf[par^1] (chunk k-1) were lgkm-drained before their MFMAs,
//     which precede their barrier arrival.  gll16 is side-effecting -> not
//     hoisted above s_barrier.  sched_barrier(0) between STAGE_X and LOAD_B
//     pins issue order so vmcnt(8) counts exactly the right ops.
//  2. Grid reverted to R2's known-good mapping (MSPLIT=8, dim3(128,8),
//     plain blockIdx): R3's remap raised FETCH_SIZE 440->759 MB and the
//     latency-exposed misses ate the pipeline gain.
//  - Z stays direct global->reg (each wave reads only its own 64 Z rows --
//    zero cross-wave reuse; LDS staging of Z was pure overhead).  X (4-wave
//    reuse) stays in LDS, double-buffered, gll16 + XOR swizzle.
//  - launch_bounds(256,2): regs MUST NOT spill (R2 lesson).
// ---------------------------------------------------------------------------

#define STAGE_X(PAR, KBASE) do {                                              \
    _Pragma("unroll")                                                         \
    for (int i_ = 0; i_ < 2; ++i_) {                                          \
        int lin_ = t + i_ * 256;              /* 16B unit index */            \
        int row_ = lin_ >> 3, c_ = lin_ & 7;                                  \
        gll16(&lds_x[PAR][lin_ * 8],                                          \
              Xb + (size_t)(row0 + row_) * D_DIM + (KBASE) +                  \
                  ((c_ ^ (row_ & 7)) * 8));                                   \
    } } while (0)

#define LOAD_B(DST, M0, KBASE) do {                                           \
    _Pragma("unroll")                                                         \
    for (int kt_ = 0; kt_ < 2; ++kt_)                                         \
        _Pragma("unroll")                                                     \
        for (int jt_ = 0; jt_ < 4; ++jt_)                                     \
            DST[kt_ * 4 + jt_] = *(const bf16x8*)(Zb +                        \
                (size_t)((M0) + wave * 64 + jt_ * 16 + l16) * D_DIM +         \
                (KBASE) + kt_ * 32 + quad * 8);                               \
    } while (0)

// One K-chunk of the counted-vmcnt pipeline.  PAR is a literal 0/1 (static
// Bf indexing, rule #20).  On entry the vmcnt queue holds (oldest first):
// [STAGE_X(this chunk) x2][LOAD_B(this chunk) x8].
#define CHUNK(PAR, KBASE, M0N, KBN) do {                                      \
    asm volatile("s_waitcnt vmcnt(8)" ::: "memory"); /* my X-stage landed */  \
    __builtin_amdgcn_s_barrier();                    /* no vmcnt drain */     \
    STAGE_X(PAR ^ 1, KBN);                                                    \
    __builtin_amdgcn_sched_barrier(0);   /* pin: stage older than B-loads */  \
    LOAD_B(Bf[PAR ^ 1], M0N, KBN);                                            \
    __builtin_amdgcn_sched_barrier(0);   /* pin: prefetch issued pre-MFMA */  \
    _Pragma("unroll")                                                         \
    for (int kt_ = 0; kt_ < 2; ++kt_) {                                       \
        bf16x8 a_[4];                                                         \
        _Pragma("unroll")                                                     \
        for (int it_ = 0; it_ < 4; ++it_)                                     \
            a_[it_] = *(const bf16x8*)&lds_x[PAR][                            \
                (it_ * 16 + l16) * BK + ((kt_ * 4 + quad) ^ cx) * 8];         \
        __builtin_amdgcn_s_setprio(1);                                        \
        _Pragma("unroll")                                                     \
        for (int it_ = 0; it_ < 4; ++it_)                                     \
            _Pragma("unroll")                                                 \
            for (int jt_ = 0; jt_ < 4; ++jt_)                                 \
                S[it_ * 4 + jt_] = __builtin_amdgcn_mfma_f32_16x16x32_bf16(   \
                    a_[it_], Bf[PAR][kt_ * 4 + jt_], S[it_ * 4 + jt_],        \
                    0, 0, 0);                                                 \
        __builtin_amdgcn_s_setprio(0);                                        \
    } } while (0)

__global__ void __launch_bounds__(256, 2)
fused_kernel(const unsigned short* __restrict__ Xb,
             const unsigned short* __restrict__ Zb,
             const unsigned short* __restrict__ WbT,
             const float* __restrict__ xsq,
             const float* __restrict__ zsq,
             const int* __restrict__ bwp,
             float* __restrict__ out) {
    __shared__ unsigned short lds_x[2][BM * BK];        // 16 KB X double-buffer
    __shared__ unsigned short lds_p[BM * LDSP_STRIDE];  // 33.8 KB P tile
    __shared__ float lds_xsq[BM];                       // total ~50.4 KB -> 2 blocks/CU

    const int t    = threadIdx.x;
    const int wave = t >> 6;
    const int lane = t & 63;
    const int quad = lane >> 4;
    const int l16  = lane & 15;
    const int cx   = l16 & 7;     // row&7 of every frag row this lane touches

    const int row0 = blockIdx.x * BM;          // R2 known-good mapping
    int mt     = blockIdx.y * TILES_PER_SPLIT;
    int mt_end = mt + TILES_PER_SPLIT;
    if (mt_end > M_TILES) mt_end = M_TILES;

    // bandwidth: int32 per harness convention (Python int 10); tolerate float bits too
    int bwi = *bwp;
    float bw;
    if (bwi > 0 && bwi < 1000000) bw = (float)bwi;
    else { union { int i; float f; } u; u.i = bwi; bw = u.f; }
    const float inv_bw = 1.0f / bw;

    if (t < BM) lds_xsq[t] = xsq[row0 + t];

    const f32x4 vzero = {0.f, 0.f, 0.f, 0.f};
    f32x4 Oacc[16];
    #pragma unroll
    for (int i = 0; i < 16; ++i) Oacc[i] = vzero;

    bf16x8 Bf[2][8];   // Z fragments, double-buffered in regs (64 VGPRs)

    // prologue: fill pipeline for (mt, chunk 0).  Order matters for vmcnt(8).
    STAGE_X(0, 0);
    __builtin_amdgcn_sched_barrier(0);
    LOAD_B(Bf[0], mt * BN, 0);
    __builtin_amdgcn_sched_barrier(0);

    for (; mt < mt_end; ++mt) {
        const int m0 = mt * BN;
        // clamp: last tile of split prefetches itself (valid mem, unused)
        const int m0next = (mt + 1 < mt_end) ? m0 + BN : m0;

        float zq[4];
        #pragma unroll
        for (int jt = 0; jt < 4; ++jt)
            zq[jt] = zsq[m0 + wave * 64 + jt * 16 + l16];

        f32x4 S[16];
        #pragma unroll
        for (int i = 0; i < 16; ++i) S[i] = vzero;

        // -------- Phase 1: S[64x256] = X * Z^T over D, counted-vmcnt pipe --
        #pragma unroll 1
        for (int kc = 0; kc < NCHUNK; kc += 2) {
            const int kb0 = kc * BK;
            const int kb1 = kb0 + BK;
            const bool last = (kc + 2 == NCHUNK);
            CHUNK(0, kb0, m0, kb1);
            CHUNK(1, kb1, last ? m0next : m0, last ? 0 : kb1 + BK);
        }
        // in flight now: next tile's chunk-0 X-stage + B-frags; they stay in
        // flight across Phases 2-3 (no vmcnt drain below).

        // -------- Phase 2: P = exp(-sqrt(d2)/bw) -> lds_p (bf16) --------
        #pragma unroll
        for (int it = 0; it < 4; ++it) {
            #pragma unroll
            for (int jt = 0; jt < 4; ++jt) {
                f32x4 s4 = S[it * 4 + jt];
                const int col = wave * 64 + jt * 16 + l16;
                #pragma unroll
                for (int r = 0; r < 4; ++r) {
                    const int row = it * 16 + quad * 4 + r;   // C-layout: row=(lane>>4)*4+reg
                    float d2 = lds_xsq[row] + zq[jt] - 2.0f * s4[r];
                    d2 = fmaxf(d2, 0.f);
                    float p = __expf(-sqrtf(d2) * inv_bw);
                    lds_p[row * LDSP_STRIDE + col] = f2bf(p);
                }
            }
        }
        // P-write -> P-read barrier: LDS-only drain; vmem prefetch stays live
        asm volatile("s_waitcnt lgkmcnt(0)" ::: "memory");
        __builtin_amdgcn_s_barrier();

        // -------- Phase 3: O += P[64x256] * Wtile[256x256] --------
        #pragma unroll
        for (int ks = 0; ks < 8; ++ks) {
            const int koff = ks * 32 + quad * 8;
            bf16x8 a[4], b[4];
            #pragma unroll
            for (int rt = 0; rt < 4; ++rt)
                a[rt] = *(const bf16x8*)&lds_p[(rt * 16 + l16) * LDSP_STRIDE + koff];
            #pragma unroll
            for (int ct = 0; ct < 4; ++ct) {
                const int y = wave * 64 + ct * 16 + l16;
                b[ct] = *(const bf16x8*)(WbT + (size_t)y * M_PAD + m0 + koff);
            }
            __builtin_amdgcn_s_setprio(1);
            #pragma unroll
            for (int rt = 0; rt < 4; ++rt)
                #pragma unroll
                for (int ct = 0; ct < 4; ++ct)
                    Oacc[rt * 4 + ct] = __builtin_amdgcn_mfma_f32_16x16x32_bf16(
                        a[rt], b[ct], Oacc[rt * 4 + ct], 0, 0, 0);
            __builtin_amdgcn_s_setprio(0);
        }
        // next tile's first CHUNK barrier separates these lds_p reads from
        // the next Phase-2 writes (P ds_reads are lgkm-drained pre-MFMA).
    }

    // -------- epilogue: accumulate M-splits via device-scope fp32 atomics --------
    #pragma unroll
    for (int rt = 0; rt < 4; ++rt) {
        #pragma unroll
        for (int ct = 0; ct < 4; ++ct) {
            f32x4 v = Oacc[rt * 4 + ct];
            const int y = wave * 64 + ct * 16 + l16;
            #pragma unroll
            for (int r = 0; r < 4; ++r) {
                const int row = row0 + rt * 16 + quad * 4 + r;
                atomicAdd(&out[(size_t)row * Y_DIM + y], v[r]);
            }
        }
    }
}

extern "C" void kernel_launch(void* const* d_in, const int* in_sizes, int n_in,
                              void* d_out, int out_size, void* d_ws, size_t ws_size,
                              hipStream_t stream) {
    const float* X = (const float*)d_in[0];
    const float* Z = (const float*)d_in[1];
    const float* W = (const float*)d_in[2];
    const int*  bw = (const int*)d_in[3];
    float* out = (float*)d_out;

    char* ws = (char*)d_ws;
    size_t off = 0;
    unsigned short* Xb  = (unsigned short*)(ws + off); off += (size_t)N_ROWS * D_DIM * 2;
    unsigned short* Zb  = (unsigned short*)(ws + off); off += (size_t)M_PAD * D_DIM * 2;
    unsigned short* WbT = (unsigned short*)(ws + off); off += (size_t)Y_DIM * M_PAD * 2;
    float* xsq = (float*)(ws + off); off += (size_t)N_ROWS * 4;
    float* zsq = (float*)(ws + off); off += (size_t)M_PAD * 4;
    // total ws use: ~68.7 MB

    hipMemsetAsync(d_out, 0, (size_t)out_size * sizeof(float), stream);
    cast_rows_kernel<<<N_ROWS, 256, 0, stream>>>(X, Xb, xsq, N_ROWS);
    cast_rows_kernel<<<M_PAD, 256, 0, stream>>>(Z, Zb, zsq, M_CENT);
    cast_wT_kernel<<<dim3(M_PAD / 32, Y_DIM / 32), 256, 0, stream>>>(W, WbT);
    fused_kernel<<<dim3(N_ROWS / BM, MSPLIT), 256, 0, stream>>>(
        Xb, Zb, WbT, xsq, zsq, bw, out);
}

// Round 4
// 816.736 us; speedup vs baseline: 1.2665x; 1.2665x over previous
//
#include <hip/hip_runtime.h>
#include <stdint.h>

// Problem constants
#define N_ROWS 8192
#define D_DIM  1024
#define M_CENT 20000
#define M_PAD  20224          // 79 * 256
#define M_TILES 79            // 256-wide center tiles
#define Y_DIM  256
#define BM 128                // rows of X per block (halves Z+W bytes/FLOP vs 64)
#define BN 256                // centers per M-iteration
#define BK 64                 // K-chunk of D
#define NCHUNK 16             // D_DIM / BK
#define MSPLIT 4
#define TILES_PER_SPLIT 20    // ceil(79/4)
#define LDSP_STRIDE 264       // 256 + 8 pad: 33 16B-slots/row == 1 mod 8 -> conflict-free

// LDS layout (u16 element offsets into lds_all):
//   buf0: [0, 24576)        = X[128][64] (8192) + Z[256][64] (16384)
//   buf1: [24576, 49152)    = same, second stage buffer
//   p   : [24576, 58368)    = P[128][264]  -- OVERLAPS buf1 ONLY; buf0 stays
//                             free so next-tile chunk-0 prefetch can fly
//                             during Phases 2-3.
#define BUFE 24576            // elements per stage buffer
#define ZOFF 8192             // Z offset within a buffer
#define POFF 24576            // p region start
#define LDS_ALL_E 58368       // total elements (116736 B; +xsq = 114.5 KiB)

typedef __attribute__((ext_vector_type(4))) float  f32x4;
typedef __attribute__((ext_vector_type(8))) __bf16 bf16x8;

__device__ __forceinline__ unsigned short f2bf(float f) {
    union { float f; unsigned u; } v; v.f = f;
    unsigned u = v.u;
    u += 0x7FFFu + ((u >> 16) & 1u);   // RNE
    return (unsigned short)(u >> 16);
}

// async global->LDS, 16B per lane. LDS dest must be wave-uniform base + lane*16.
__device__ __forceinline__ void gll16(void* lds, const void* g) {
    __builtin_amdgcn_global_load_lds(
        (const __attribute__((address_space(1))) void*)g,
        (__attribute__((address_space(3))) void*)lds, 16, 0, 0);
}

// cast fp32 rows -> bf16, compute fp32 row sum-of-squares; pad rows -> zeros
__global__ void cast_rows_kernel(const float* __restrict__ src,
                                 unsigned short* __restrict__ dst,
                                 float* __restrict__ sq, int nrows_valid) {
    int row = blockIdx.x;
    int t = threadIdx.x;  // 256 threads, 4 floats each = 1024 = D_DIM
    float s = 0.f;
    if (row < nrows_valid) {
        float4 v = ((const float4*)(src + (size_t)row * D_DIM))[t];
        s = v.x * v.x + v.y * v.y + v.z * v.z + v.w * v.w;
        ushort4 o;
        o.x = f2bf(v.x); o.y = f2bf(v.y); o.z = f2bf(v.z); o.w = f2bf(v.w);
        ((ushort4*)(dst + (size_t)row * D_DIM))[t] = o;
    } else {
        ((ushort4*)(dst + (size_t)row * D_DIM))[t] = make_ushort4(0, 0, 0, 0);
    }
    __shared__ float red[4];
    for (int off = 32; off; off >>= 1) s += __shfl_down(s, off, 64);
    if ((t & 63) == 0) red[t >> 6] = s;
    __syncthreads();
    if (t == 0) sq[row] = red[0] + red[1] + red[2] + red[3];
}

// W [M][Y] fp32 -> WT [Y][M_PAD] bf16, pad rows (centers >= M_CENT) -> 0
__global__ void cast_wT_kernel(const float* __restrict__ w,
                               unsigned short* __restrict__ wT) {
    __shared__ float tile[32][33];
    int k0 = blockIdx.x * 32;   // center dim
    int y0 = blockIdx.y * 32;   // Y dim
    int tx = threadIdx.x & 31;
    int ty = threadIdx.x >> 5;  // 0..7
    #pragma unroll
    for (int i = 0; i < 4; ++i) {
        int k = k0 + ty + i * 8;
        float v = (k < M_CENT) ? w[(size_t)k * Y_DIM + y0 + tx] : 0.f;
        tile[tx][ty + i * 8] = v;     // tile[y_local][k_local]
    }
    __syncthreads();
    #pragma unroll
    for (int i = 0; i < 4; ++i) {
        int yl = ty + i * 8;
        wT[(size_t)(y0 + yl) * M_PAD + k0 + tx] = f2bf(tile[yl][tx]);
    }
}

// ---------------------------------------------------------------------------
// R6 = R5 hardened (R5: container failed twice, no counters; audit found no
// race/deadlock; sole new resource-class risk was 137.7KB static LDS):
//  - lds_zsq (20.5KB) DROPPED: per-tile zsq -> 4 register loads at tile top.
//    The CHUNK(0) vmcnt(6) already guarantees their completion before
//    Phase 2 (it drains everything older than the just-issued stage), so
//    this costs zero extra waits and removes all Phase-2 vmem.
//    Total LDS 137.7 -> 114.5 KiB.
//  - Everything else unchanged from R5:
//    * BM=128, 512 thr, 8 waves (wx x-half, wm m-slab); grid 64x4 = 256
//      blocks = 1/CU; Z+W cache bytes per FLOP halved vs R2.
//    * Counted-vmcnt raw-barrier pipeline (T3+T4), zero persistent VGPRs:
//        barA -> STAGE(next buf, 6 gll16) -> s_waitcnt vmcnt(6) -> barB
//        -> ds_read frags -> 32 MFMA.   vmcnt NEVER drains to 0 in phase 1.
//    * p overlaps buf1 only; chunk-15 prefetches next tile's chunk-0 into
//      buf0, landing during Phases 2-3.
//    * All-LDS staging via global_load_lds (R4 lesson: Z-in-VGPR spilled
//      ~114MB scratch; WRITE_SIZE is the spill sentinel).
//  - launch_bounds(512,2): cap 256 regs/wave, S+Oacc in AGPRs, no spill.
// ---------------------------------------------------------------------------

#define STAGE(PAR, M0, KBASE) do {                                            \
    _Pragma("unroll")                                                         \
    for (int i_ = 0; i_ < 2; ++i_) {          /* X: 1024 16B-chunks */        \
        int lin_ = t + i_ * 512;                                              \
        int row_ = lin_ >> 3, c_ = lin_ & 7;                                  \
        gll16(&lds_all[(PAR) * BUFE + lin_ * 8],                              \
              Xb + (size_t)(row0 + row_) * D_DIM + (KBASE) +                  \
                  ((c_ ^ (row_ & 7)) * 8));                                   \
    }                                                                         \
    _Pragma("unroll")                                                         \
    for (int i_ = 0; i_ < 4; ++i_) {          /* Z: 2048 16B-chunks */        \
        int lin_ = t + i_ * 512;                                              \
        int row_ = lin_ >> 3, c_ = lin_ & 7;                                  \
        gll16(&lds_all[(PAR) * BUFE + ZOFF + lin_ * 8],                       \
              Zb + (size_t)((M0) + row_) * D_DIM + (KBASE) +                  \
                  ((c_ ^ (row_ & 7)) * 8));                                   \
    } } while (0)

// One K-chunk.  PAR literal 0/1.  On entry: [stage(kc)x6] outstanding
// (issued one chunk earlier), buf[PAR^1]'s readers all passed barA.
// vmcnt(6) leaves the 6 YOUNGEST ops (the stage just issued) outstanding and
// drains everything older -- count stays correct even with stray older loads.
#define CHUNK(PAR, M0N, KBN) do {                                             \
    asm volatile("" ::: "memory");                                            \
    __builtin_amdgcn_s_barrier();          /* barA: buf[PAR^1] free */        \
    asm volatile("" ::: "memory");                                            \
    STAGE(PAR ^ 1, M0N, KBN);                                                 \
    __builtin_amdgcn_sched_barrier(0);                                        \
    asm volatile("s_waitcnt vmcnt(6)" ::: "memory"); /* my stage(kc) done */  \
    __builtin_amdgcn_s_barrier();          /* barB: everyone's stage done */  \
    asm volatile("" ::: "memory");                                            \
    _Pragma("unroll")                                                         \
    for (int kt_ = 0; kt_ < 2; ++kt_) {                                       \
        const int sw_ = ((kt_ * 4 + quad) ^ cx) * 8;                          \
        bf16x8 a_[4], b_[4];                                                  \
        _Pragma("unroll")                                                     \
        for (int it_ = 0; it_ < 4; ++it_)                                     \
            a_[it_] = *(const bf16x8*)&lds_all[(PAR) * BUFE +                 \
                (wx * 64 + it_ * 16 + l16) * BK + sw_];                       \
        _Pragma("unroll")                                                     \
        for (int jt_ = 0; jt_ < 4; ++jt_)                                     \
            b_[jt_] = *(const bf16x8*)&lds_all[(PAR) * BUFE + ZOFF +          \
                (wm * 64 + jt_ * 16 + l16) * BK + sw_];                       \
        __builtin_amdgcn_s_setprio(1);                                        \
        _Pragma("unroll")                                                     \
        for (int it_ = 0; it_ < 4; ++it_)                                     \
            _Pragma("unroll")                                                 \
            for (int jt_ = 0; jt_ < 4; ++jt_)                                 \
                S[it_ * 4 + jt_] = __builtin_amdgcn_mfma_f32_16x16x32_bf16(   \
                    a_[it_], b_[jt_], S[it_ * 4 + jt_], 0, 0, 0);             \
        __builtin_amdgcn_s_setprio(0);                                        \
    } } while (0)

__global__ void __launch_bounds__(512, 2)
fused_kernel(const unsigned short* __restrict__ Xb,
             const unsigned short* __restrict__ Zb,
             const unsigned short* __restrict__ WbT,
             const float* __restrict__ xsq,
             const float* __restrict__ zsq,
             const int* __restrict__ bwp,
             float* __restrict__ out) {
    __shared__ unsigned short lds_all[LDS_ALL_E];            // 116.7 KB
    __shared__ float lds_xsq[BM];                            // 0.5 KB (114.5 KiB total)

    const int t    = threadIdx.x;
    const int wave = t >> 6;
    const int wx   = wave >> 2;   // x-half: 0..1 (64 rows each)
    const int wm   = wave & 3;    // m-slab: 0..3 (64 centers each)
    const int lane = t & 63;
    const int quad = lane >> 4;
    const int l16  = lane & 15;
    const int cx   = l16 & 7;     // row&7 of every frag row this lane touches

    const int row0 = blockIdx.x * BM;
    const int mt0  = blockIdx.y * TILES_PER_SPLIT;
    int mt_end = mt0 + TILES_PER_SPLIT;
    if (mt_end > M_TILES) mt_end = M_TILES;

    // bandwidth: int32 per harness convention (Python int 10); tolerate float bits too
    int bwi = *bwp;
    float bw;
    if (bwi > 0 && bwi < 1000000) bw = (float)bwi;
    else { union { int i; float f; } u; u.i = bwi; bw = u.f; }
    const float inv_bw = 1.0f / bw;

    if (t < BM) lds_xsq[t] = xsq[row0 + t];

    const f32x4 vzero = {0.f, 0.f, 0.f, 0.f};
    f32x4 Oacc[16];
    #pragma unroll
    for (int i = 0; i < 16; ++i) Oacc[i] = vzero;

    // prologue: stage (tile mt0, chunk 0) -> buf0
    STAGE(0, mt0 * BN, 0);
    __builtin_amdgcn_sched_barrier(0);

    for (int mt = mt0; mt < mt_end; ++mt) {
        const int m0 = mt * BN;
        // last tile of split prefetches itself (valid mem, unused)
        const int m0next = (mt + 1 < mt_end) ? m0 + BN : m0;

        // zsq for this tile -> registers (4 x 4B); completion guaranteed by
        // the vmcnt(6) inside CHUNK(0) below (these are older than the stage).
        float zq[4];
        #pragma unroll
        for (int jt = 0; jt < 4; ++jt)
            zq[jt] = zsq[m0 + wm * 64 + jt * 16 + l16];

        f32x4 S[16];
        #pragma unroll
        for (int i = 0; i < 16; ++i) S[i] = vzero;

        // -------- Phase 1: S[128x256] = X * Z^T over D, counted-vmcnt pipe --
        // chunk kc reads buf[kc&1]; stages kc+1 into buf[(kc+1)&1].
        // kc=15 stages NEXT TILE's chunk 0 into buf0 (disjoint from p),
        // landing during Phases 2-3 -> no drain at tile boundary.
        #pragma unroll 1
        for (int kc = 0; kc < NCHUNK; kc += 2) {
            const bool last = (kc + 2 == NCHUNK);
            CHUNK(0, m0, (kc + 1) * BK);
            CHUNK(1, last ? m0next : m0, last ? 0 : (kc + 2) * BK);
        }

        // phase1 -> phase2: all buf1 readers done before p overwrites it
        asm volatile("" ::: "memory");
        __builtin_amdgcn_s_barrier();
        asm volatile("" ::: "memory");

        // -------- Phase 2: P = exp(-sqrt(d2)/bw) -> p (bf16) --------
        #pragma unroll
        for (int it = 0; it < 4; ++it) {
            #pragma unroll
            for (int jt = 0; jt < 4; ++jt) {
                f32x4 s4 = S[it * 4 + jt];
                const int col = wm * 64 + jt * 16 + l16;
                #pragma unroll
                for (int r = 0; r < 4; ++r) {
                    const int row = wx * 64 + it * 16 + quad * 4 + r; // C-layout
                    float d2 = lds_xsq[row] + zq[jt] - 2.0f * s4[r];
                    d2 = fmaxf(d2, 0.f);
                    float p = __expf(-sqrtf(d2) * inv_bw);
                    lds_all[POFF + row * LDSP_STRIDE + col] = f2bf(p);
                }
            }
        }
        // P-write -> P-read: LDS-only drain; buf0 prefetch stays in flight
        asm volatile("s_waitcnt lgkmcnt(0)" ::: "memory");
        __builtin_amdgcn_s_barrier();
        asm volatile("" ::: "memory");

        // -------- Phase 3: O += P[128x256] * Wtile[256x256] --------
        // wave (wx,wm): O rows wx*64..+63, y-slab wm*64..+63, full m=256.
        #pragma unroll
        for (int ks = 0; ks < 8; ++ks) {
            const int koff = ks * 32 + quad * 8;
            bf16x8 a[4], b[4];
            #pragma unroll
            for (int rt = 0; rt < 4; ++rt)
                a[rt] = *(const bf16x8*)&lds_all[POFF +
                    (wx * 64 + rt * 16 + l16) * LDSP_STRIDE + koff];
            #pragma unroll
            for (int ct = 0; ct < 4; ++ct) {
                const int y = wm * 64 + ct * 16 + l16;
                b[ct] = *(const bf16x8*)(WbT + (size_t)y * M_PAD + m0 + koff);
            }
            __builtin_amdgcn_s_setprio(1);
            #pragma unroll
            for (int rt = 0; rt < 4; ++rt)
                #pragma unroll
                for (int ct = 0; ct < 4; ++ct)
                    Oacc[rt * 4 + ct] = __builtin_amdgcn_mfma_f32_16x16x32_bf16(
                        a[rt], b[ct], Oacc[rt * 4 + ct], 0, 0, 0);
            __builtin_amdgcn_s_setprio(0);
        }
        // next tile's CHUNK(0) barA separates these p reads from the next
        // stage writes into buf1 (p ds_reads are lgkm-drained pre-MFMA).
    }

    // drain the dangling last-tile prefetch before LDS is released
    asm volatile("s_waitcnt vmcnt(0)" ::: "memory");

    // -------- epilogue: accumulate M-splits via device-scope fp32 atomics ----
    #pragma unroll
    for (int rt = 0; rt < 4; ++rt) {
        #pragma unroll
        for (int ct = 0; ct < 4; ++ct) {
            f32x4 v = Oacc[rt * 4 + ct];
            const int y = wm * 64 + ct * 16 + l16;
            #pragma unroll
            for (int r = 0; r < 4; ++r) {
                const int row = row0 + wx * 64 + rt * 16 + quad * 4 + r;
                atomicAdd(&out[(size_t)row * Y_DIM + y], v[r]);
            }
        }
    }
}

extern "C" void kernel_launch(void* const* d_in, const int* in_sizes, int n_in,
                              void* d_out, int out_size, void* d_ws, size_t ws_size,
                              hipStream_t stream) {
    const float* X = (const float*)d_in[0];
    const float* Z = (const float*)d_in[1];
    const float* W = (const float*)d_in[2];
    const int*  bw = (const int*)d_in[3];
    float* out = (float*)d_out;

    char* ws = (char*)d_ws;
    size_t off = 0;
    unsigned short* Xb  = (unsigned short*)(ws + off); off += (size_t)N_ROWS * D_DIM * 2;
    unsigned short* Zb  = (unsigned short*)(ws + off); off += (size_t)M_PAD * D_DIM * 2;
    unsigned short* WbT = (unsigned short*)(ws + off); off += (size_t)Y_DIM * M_PAD * 2;
    float* xsq = (float*)(ws + off); off += (size_t)N_ROWS * 4;
    float* zsq = (float*)(ws + off); off += (size_t)M_PAD * 4;
    // total ws use: ~68.7 MB

    hipMemsetAsync(d_out, 0, (size_t)out_size * sizeof(float), stream);
    cast_rows_kernel<<<N_ROWS, 256, 0, stream>>>(X, Xb, xsq, N_ROWS);
    cast_rows_kernel<<<M_PAD, 256, 0, stream>>>(Z, Zb, zsq, M_CENT);
    cast_wT_kernel<<<dim3(M_PAD / 32, Y_DIM / 32), 256, 0, stream>>>(W, WbT);
    fused_kernel<<<dim3(N_ROWS / BM, MSPLIT), 512, 0, stream>>>(
        Xb, Zb, WbT, xsq, zsq, bw, out);
}

// Round 5
// 777.980 us; speedup vs baseline: 1.3296x; 1.0498x over previous
//
#include <hip/hip_runtime.h>
#include <stdint.h>

// Problem constants
#define N_ROWS 8192
#define D_DIM  1024
#define M_CENT 20000
#define M_PAD  20224          // 79 * 256
#define M_TILES 79            // 256-wide center tiles
#define Y_DIM  256
#define BM 64                 // rows of X per block (R7: back to 64 -> 2 blocks/CU)
#define BN 256                // centers per M-iteration (wave tile 64x64)
#define BK 64                 // K-chunk of D
#define NCHUNK 16             // D_DIM / BK
#define MSPLIT 8
#define TILES_PER_SPLIT 10    // ceil(79/8)
#define LDSP_STRIDE 264       // 256 + 8 pad: 33 16B-slots/row == 1 mod 8 -> conflict-free

// LDS layout (u16 element offsets into lds_all):
//   buf0: [0, 20480)        = X[64][64] (4096) + Z[256][64] (16384)
//   buf1: [20480, 40960)    = same, second stage buffer
//   p   : [20480, 37376)    = P[64][264] (16896) -- aliases buf1 ONLY; buf0
//                             stays free so next-tile chunk-0 prefetch flies
//                             during Phases 2-3.
// Total 40960 elem = 81920 B = EXACTLY half of 160KB -> 2 blocks/CU.
// (512-B LDS granularity divides 81920; R2/R6 reported sizes confirm no pad.)
// xsq/zsq live in REGISTERS (no LDS arrays) to preserve the exact fit.
#define BUFE 20480            // elements per stage buffer
#define ZOFF 4096             // Z offset within a buffer
#define POFF 20480            // p region start (== buf1)

typedef __attribute__((ext_vector_type(4))) float  f32x4;
typedef __attribute__((ext_vector_type(8))) __bf16 bf16x8;

__device__ __forceinline__ unsigned short f2bf(float f) {
    union { float f; unsigned u; } v; v.f = f;
    unsigned u = v.u;
    u += 0x7FFFu + ((u >> 16) & 1u);   // RNE
    return (unsigned short)(u >> 16);
}

// async global->LDS, 16B per lane. LDS dest must be wave-uniform base + lane*16.
__device__ __forceinline__ void gll16(void* lds, const void* g) {
    __builtin_amdgcn_global_load_lds(
        (const __attribute__((address_space(1))) void*)g,
        (__attribute__((address_space(3))) void*)lds, 16, 0, 0);
}

// cast fp32 rows -> bf16, compute fp32 row sum-of-squares; pad rows -> zeros
__global__ void cast_rows_kernel(const float* __restrict__ src,
                                 unsigned short* __restrict__ dst,
                                 float* __restrict__ sq, int nrows_valid) {
    int row = blockIdx.x;
    int t = threadIdx.x;  // 256 threads, 4 floats each = 1024 = D_DIM
    float s = 0.f;
    if (row < nrows_valid) {
        float4 v = ((const float4*)(src + (size_t)row * D_DIM))[t];
        s = v.x * v.x + v.y * v.y + v.z * v.z + v.w * v.w;
        ushort4 o;
        o.x = f2bf(v.x); o.y = f2bf(v.y); o.z = f2bf(v.z); o.w = f2bf(v.w);
        ((ushort4*)(dst + (size_t)row * D_DIM))[t] = o;
    } else {
        ((ushort4*)(dst + (size_t)row * D_DIM))[t] = make_ushort4(0, 0, 0, 0);
    }
    __shared__ float red[4];
    for (int off = 32; off; off >>= 1) s += __shfl_down(s, off, 64);
    if ((t & 63) == 0) red[t >> 6] = s;
    __syncthreads();
    if (t == 0) sq[row] = red[0] + red[1] + red[2] + red[3];
}

// W [M][Y] fp32 -> WT [Y][M_PAD] bf16, pad rows (centers >= M_CENT) -> 0
__global__ void cast_wT_kernel(const float* __restrict__ w,
                               unsigned short* __restrict__ wT) {
    __shared__ float tile[32][33];
    int k0 = blockIdx.x * 32;   // center dim
    int y0 = blockIdx.y * 32;   // Y dim
    int tx = threadIdx.x & 31;
    int ty = threadIdx.x >> 5;  // 0..7
    #pragma unroll
    for (int i = 0; i < 4; ++i) {
        int k = k0 + ty + i * 8;
        float v = (k < M_CENT) ? w[(size_t)k * Y_DIM + y0 + tx] : 0.f;
        tile[tx][ty + i * 8] = v;     // tile[y_local][k_local]
    }
    __syncthreads();
    #pragma unroll
    for (int i = 0; i < 4; ++i) {
        int yl = ty + i * 8;
        wT[(size_t)(y0 + yl) * M_PAD + k0 + tx] = f2bf(tile[yl][tx]);
    }
}

// ---------------------------------------------------------------------------
// R7 (post-mortem of R6: counted-vmcnt pipe correct in HW but 1 block/CU
// serializes phases -> 733us; R2's 2-block overlap at 644us beat it despite
// naive per-chunk drains.  Cross-block overlap > intra-block pipelining):
//  = R2 geometry (BM=64, 4 waves, MSPLIT=8, 1024 blocks, 2 resident/CU)
//  + R6 counted-vmcnt raw-barrier pipeline (T3+T4, HW-verified):
//      barA -> STAGE(next buf, 10 gll16) -> s_waitcnt vmcnt(10) -> barB
//      -> ds_read frags -> 32 MFMA.   vmcnt NEVER drains to 0 in phase 1.
//    vmcnt(10) = ops-just-issued; drains EVERYTHING older (incl. stray zsq
//    scalar loads) -> count robust.  p aliases buf1 only; chunk-15 stages
//    next tile's chunk-0 into buf0, landing during Phases 2-3.
//  + xsq/zsq in registers (4 float4 + 4 scalars/thread): LDS = exactly
//    81920 B -> two blocks fit in 160KB.  LDS_Block_Size is the sentinel.
//  + v_sqrt_f32 inline (1 inst vs libm fixup seq; err << bf16 floor).
//  - launch_bounds(256,2): 8 waves/CU = 2/SIMD -> 256-reg cap, no spill
//    (WRITE_SIZE sentinel: ~75 MB expected; >=140 means spill).
// ---------------------------------------------------------------------------

#define STAGE(PAR, M0, KBASE) do {                                            \
    _Pragma("unroll")                                                         \
    for (int i_ = 0; i_ < 2; ++i_) {          /* X: 512 16B-chunks */         \
        int lin_ = t + i_ * 256;                                              \
        int row_ = lin_ >> 3, c_ = lin_ & 7;                                  \
        gll16(&lds_all[(PAR) * BUFE + lin_ * 8],                              \
              Xb + (size_t)(row0 + row_) * D_DIM + (KBASE) +                  \
                  ((c_ ^ (row_ & 7)) * 8));                                   \
    }                                                                         \
    _Pragma("unroll")                                                         \
    for (int i_ = 0; i_ < 8; ++i_) {          /* Z: 2048 16B-chunks */        \
        int lin_ = t + i_ * 256;                                              \
        int row_ = lin_ >> 3, c_ = lin_ & 7;                                  \
        gll16(&lds_all[(PAR) * BUFE + ZOFF + lin_ * 8],                       \
              Zb + (size_t)((M0) + row_) * D_DIM + (KBASE) +                  \
                  ((c_ ^ (row_ & 7)) * 8));                                   \
    } } while (0)

// One K-chunk.  PAR literal 0/1.  On entry: [stage(kc)x10] outstanding
// (issued one chunk earlier); buf[PAR^1]'s readers all passed barA.
// vmcnt(10) keeps the 10 JUST-ISSUED ops outstanding and drains everything
// older (stage(kc) + any stray scalar loads) -- robust counting.
#define CHUNK(PAR, M0N, KBN) do {                                             \
    asm volatile("" ::: "memory");                                            \
    __builtin_amdgcn_s_barrier();          /* barA: buf[PAR^1] free */        \
    asm volatile("" ::: "memory");                                            \
    STAGE(PAR ^ 1, M0N, KBN);                                                 \
    __builtin_amdgcn_sched_barrier(0);                                        \
    asm volatile("s_waitcnt vmcnt(10)" ::: "memory"); /* stage(kc) done */    \
    __builtin_amdgcn_s_barrier();          /* barB: everyone's stage done */  \
    asm volatile("" ::: "memory");                                            \
    _Pragma("unroll")                                                         \
    for (int kt_ = 0; kt_ < 2; ++kt_) {                                       \
        const int sw_ = ((kt_ * 4 + quad) ^ cx) * 8;                          \
        bf16x8 a_[4], b_[4];                                                  \
        _Pragma("unroll")                                                     \
        for (int it_ = 0; it_ < 4; ++it_)                                     \
            a_[it_] = *(const bf16x8*)&lds_all[(PAR) * BUFE +                 \
                (it_ * 16 + l16) * BK + sw_];                                 \
        _Pragma("unroll")                                                     \
        for (int jt_ = 0; jt_ < 4; ++jt_)                                     \
            b_[jt_] = *(const bf16x8*)&lds_all[(PAR) * BUFE + ZOFF +          \
                (wave * 64 + jt_ * 16 + l16) * BK + sw_];                     \
        __builtin_amdgcn_s_setprio(1);                                        \
        _Pragma("unroll")                                                     \
        for (int it_ = 0; it_ < 4; ++it_)                                     \
            _Pragma("unroll")                                                 \
            for (int jt_ = 0; jt_ < 4; ++jt_)                                 \
                S[it_ * 4 + jt_] = __builtin_amdgcn_mfma_f32_16x16x32_bf16(   \
                    a_[it_], b_[jt_], S[it_ * 4 + jt_], 0, 0, 0);             \
        __builtin_amdgcn_s_setprio(0);                                        \
    } } while (0)

__global__ void __launch_bounds__(256, 2)
fused_kernel(const unsigned short* __restrict__ Xb,
             const unsigned short* __restrict__ Zb,
             const unsigned short* __restrict__ WbT,
             const float* __restrict__ xsq,
             const float* __restrict__ zsq,
             const int* __restrict__ bwp,
             float* __restrict__ out) {
    __shared__ unsigned short lds_all[2 * BUFE];   // EXACTLY 81920 B

    const int t    = threadIdx.x;
    const int wave = t >> 6;      // 0..3: m-slab (phase1 B, phase3 y-slab)
    const int lane = t & 63;
    const int quad = lane >> 4;
    const int l16  = lane & 15;
    const int cx   = l16 & 7;     // row&7 of every frag row this lane touches

    const int row0 = blockIdx.x * BM;          // R2 known-good mapping
    const int mt0  = blockIdx.y * TILES_PER_SPLIT;
    int mt_end = mt0 + TILES_PER_SPLIT;
    if (mt_end > M_TILES) mt_end = M_TILES;

    // bandwidth: int32 per harness convention (Python int 10); tolerate float bits too
    int bwi = *bwp;
    float bw;
    if (bwi > 0 && bwi < 1000000) bw = (float)bwi;
    else { union { int i; float f; } u; u.i = bwi; bw = u.f; }
    const float inv_bw = 1.0f / bw;

    // xsq -> registers: this thread's 16 rows are it*16 + quad*4 + r.
    // 16B-aligned f32x4 loads (row0 %64==0, quad*16B).  Completion swept by
    // the first CHUNK's vmcnt(10) (older than the just-issued stage).
    f32x4 xq[4];
    #pragma unroll
    for (int it = 0; it < 4; ++it)
        xq[it] = *(const f32x4*)(xsq + row0 + it * 16 + quad * 4);

    const f32x4 vzero = {0.f, 0.f, 0.f, 0.f};
    f32x4 Oacc[16];
    #pragma unroll
    for (int i = 0; i < 16; ++i) Oacc[i] = vzero;

    // prologue: stage (tile mt0, chunk 0) -> buf0
    STAGE(0, mt0 * BN, 0);
    __builtin_amdgcn_sched_barrier(0);

    for (int mt = mt0; mt < mt_end; ++mt) {
        const int m0 = mt * BN;
        // last tile of split prefetches itself (valid mem, unused)
        const int m0next = (mt + 1 < mt_end) ? m0 + BN : m0;

        // zsq for this tile -> registers; swept by CHUNK(0)'s vmcnt(10).
        float zq[4];
        #pragma unroll
        for (int jt = 0; jt < 4; ++jt)
            zq[jt] = zsq[m0 + wave * 64 + jt * 16 + l16];

        f32x4 S[16];
        #pragma unroll
        for (int i = 0; i < 16; ++i) S[i] = vzero;

        // -------- Phase 1: S[64x256] = X * Z^T over D, counted-vmcnt pipe --
        // chunk kc reads buf[kc&1]; stages kc+1 into buf[(kc+1)&1].
        // kc=15 stages NEXT TILE's chunk 0 into buf0 (disjoint from p),
        // landing during Phases 2-3 -> no drain at tile boundary.
        #pragma unroll 1
        for (int kc = 0; kc < NCHUNK; kc += 2) {
            const bool last = (kc + 2 == NCHUNK);
            CHUNK(0, m0, (kc + 1) * BK);
            CHUNK(1, last ? m0next : m0, last ? 0 : (kc + 2) * BK);
        }

        // phase1 -> phase2: all buf1 readers done before p overwrites it
        asm volatile("" ::: "memory");
        __builtin_amdgcn_s_barrier();
        asm volatile("" ::: "memory");

        // -------- Phase 2: P = exp(-sqrt(d2)/bw) -> p (bf16) --------
        #pragma unroll
        for (int it = 0; it < 4; ++it) {
            #pragma unroll
            for (int jt = 0; jt < 4; ++jt) {
                f32x4 s4 = S[it * 4 + jt];
                const int col = wave * 64 + jt * 16 + l16;
                #pragma unroll
                for (int r = 0; r < 4; ++r) {
                    const int row = it * 16 + quad * 4 + r;   // C-layout
                    float d2 = xq[it][r] + zq[jt] - 2.0f * s4[r];
                    d2 = fmaxf(d2, 0.f);
                    float d;
                    asm("v_sqrt_f32 %0, %1" : "=v"(d) : "v"(d2));
                    float p = __expf(-d * inv_bw);
                    lds_all[POFF + row * LDSP_STRIDE + col] = f2bf(p);
                }
            }
        }
        // P-write -> P-read: LDS-only drain; buf0 prefetch stays in flight
        asm volatile("s_waitcnt lgkmcnt(0)" ::: "memory");
        __builtin_amdgcn_s_barrier();
        asm volatile("" ::: "memory");

        // -------- Phase 3: O += P[64x256] * Wtile[256x256] --------
        #pragma unroll
        for (int ks = 0; ks < 8; ++ks) {
            const int koff = ks * 32 + quad * 8;
            bf16x8 a[4], b[4];
            #pragma unroll
            for (int rt = 0; rt < 4; ++rt)
                a[rt] = *(const bf16x8*)&lds_all[POFF +
                    (rt * 16 + l16) * LDSP_STRIDE + koff];
            #pragma unroll
            for (int ct = 0; ct < 4; ++ct) {
                const int y = wave * 64 + ct * 16 + l16;
                b[ct] = *(const bf16x8*)(WbT + (size_t)y * M_PAD + m0 + koff);
            }
            __builtin_amdgcn_s_setprio(1);
            #pragma unroll
            for (int rt = 0; rt < 4; ++rt)
                #pragma unroll
                for (int ct = 0; ct < 4; ++ct)
                    Oacc[rt * 4 + ct] = __builtin_amdgcn_mfma_f32_16x16x32_bf16(
                        a[rt], b[ct], Oacc[rt * 4 + ct], 0, 0, 0);
            __builtin_amdgcn_s_setprio(0);
        }
        // next tile's CHUNK(0) barA separates these p reads from the next
        // stage writes into buf1 (p ds_reads are lgkm-drained pre-MFMA).
    }

    // drain the dangling last-tile prefetch before LDS is released
    asm volatile("s_waitcnt vmcnt(0)" ::: "memory");

    // -------- epilogue: accumulate M-splits via device-scope fp32 atomics ----
    #pragma unroll
    for (int rt = 0; rt < 4; ++rt) {
        #pragma unroll
        for (int ct = 0; ct < 4; ++ct) {
            f32x4 v = Oacc[rt * 4 + ct];
            const int y = wave * 64 + ct * 16 + l16;
            #pragma unroll
            for (int r = 0; r < 4; ++r) {
                const int row = row0 + rt * 16 + quad * 4 + r;
                atomicAdd(&out[(size_t)row * Y_DIM + y], v[r]);
            }
        }
    }
}

extern "C" void kernel_launch(void* const* d_in, const int* in_sizes, int n_in,
                              void* d_out, int out_size, void* d_ws, size_t ws_size,
                              hipStream_t stream) {
    const float* X = (const float*)d_in[0];
    const float* Z = (const float*)d_in[1];
    const float* W = (const float*)d_in[2];
    const int*  bw = (const int*)d_in[3];
    float* out = (float*)d_out;

    char* ws = (char*)d_ws;
    size_t off = 0;
    unsigned short* Xb  = (unsigned short*)(ws + off); off += (size_t)N_ROWS * D_DIM * 2;
    unsigned short* Zb  = (unsigned short*)(ws + off); off += (size_t)M_PAD * D_DIM * 2;
    unsigned short* WbT = (unsigned short*)(ws + off); off += (size_t)Y_DIM * M_PAD * 2;
    float* xsq = (float*)(ws + off); off += (size_t)N_ROWS * 4;
    float* zsq = (float*)(ws + off); off += (size_t)M_PAD * 4;
    // total ws use: ~68.7 MB

    hipMemsetAsync(d_out, 0, (size_t)out_size * sizeof(float), stream);
    cast_rows_kernel<<<N_ROWS, 256, 0, stream>>>(X, Xb, xsq, N_ROWS);
    cast_rows_kernel<<<M_PAD, 256, 0, stream>>>(Z, Zb, zsq, M_CENT);
    cast_wT_kernel<<<dim3(M_PAD / 32, Y_DIM / 32), 256, 0, stream>>>(W, WbT);
    fused_kernel<<<dim3(N_ROWS / BM, MSPLIT), 256, 0, stream>>>(
        Xb, Zb, WbT, xsq, zsq, bw, out);
}

// Round 6
// 711.612 us; speedup vs baseline: 1.4536x; 1.0933x over previous
//
#include <hip/hip_runtime.h>
#include <stdint.h>

// Problem constants
#define N_ROWS 8192
#define D_DIM  1024
#define M_CENT 20000
#define M_PAD  20224          // 79 * 256
#define M_TILES 79            // 256-wide center tiles
#define Y_DIM  256
#define BM 64                 // rows of X per block (2 blocks/CU geometry)
#define BN 256                // centers per M-iteration (wave tile 64x64)
#define BK 64                 // K-chunk of D
#define NCHUNK 16             // D_DIM / BK
#define MSPLIT 8
#define TILES_PER_SPLIT 10    // ceil(79/8)
#define LDSP_STRIDE 264       // 256 + 8 pad: 33 16B-slots/row == 1 mod 8 -> conflict-free

// LDS layout (u16 element offsets into lds_all):
//   buf0: [0, 20480)        = X[64][64] (4096) + Z[256][64] (16384)
//   buf1: [20480, 40960)    = same, second stage buffer
//   p   : [20480, 37376)    = P[64][264] (16896) -- aliases buf1 ONLY; buf0
//                             stays free so next-tile chunk-0 prefetch flies
//                             during Phases 2-3.
// Total 40960 elem = 81920 B = EXACTLY half of 160KB -> 2 blocks/CU
// (R7 HW-verified: LDS_Block_Size=81920, Occupancy 22% = 2 blocks/CU).
#define BUFE 20480            // elements per stage buffer
#define ZOFF 4096             // Z offset within a buffer
#define POFF 20480            // p region start (== buf1)

typedef __attribute__((ext_vector_type(4))) float  f32x4;
typedef __attribute__((ext_vector_type(8))) __bf16 bf16x8;

__device__ __forceinline__ unsigned short f2bf(float f) {
    union { float f; unsigned u; } v; v.f = f;
    unsigned u = v.u;
    u += 0x7FFFu + ((u >> 16) & 1u);   // RNE
    return (unsigned short)(u >> 16);
}

// async global->LDS, 16B per lane. LDS dest must be wave-uniform base + lane*16.
__device__ __forceinline__ void gll16(void* lds, const void* g) {
    __builtin_amdgcn_global_load_lds(
        (const __attribute__((address_space(1))) void*)g,
        (__attribute__((address_space(3))) void*)lds, 16, 0, 0);
}

// cast fp32 rows -> bf16, compute fp32 row sum-of-squares; pad rows -> zeros
__global__ void cast_rows_kernel(const float* __restrict__ src,
                                 unsigned short* __restrict__ dst,
                                 float* __restrict__ sq, int nrows_valid) {
    int row = blockIdx.x;
    int t = threadIdx.x;  // 256 threads, 4 floats each = 1024 = D_DIM
    float s = 0.f;
    if (row < nrows_valid) {
        float4 v = ((const float4*)(src + (size_t)row * D_DIM))[t];
        s = v.x * v.x + v.y * v.y + v.z * v.z + v.w * v.w;
        ushort4 o;
        o.x = f2bf(v.x); o.y = f2bf(v.y); o.z = f2bf(v.z); o.w = f2bf(v.w);
        ((ushort4*)(dst + (size_t)row * D_DIM))[t] = o;
    } else {
        ((ushort4*)(dst + (size_t)row * D_DIM))[t] = make_ushort4(0, 0, 0, 0);
    }
    __shared__ float red[4];
    for (int off = 32; off; off >>= 1) s += __shfl_down(s, off, 64);
    if ((t & 63) == 0) red[t >> 6] = s;
    __syncthreads();
    if (t == 0) sq[row] = red[0] + red[1] + red[2] + red[3];
}

// W [M][Y] fp32 -> WT [Y][M_PAD] bf16, pad rows (centers >= M_CENT) -> 0
__global__ void cast_wT_kernel(const float* __restrict__ w,
                               unsigned short* __restrict__ wT) {
    __shared__ float tile[32][33];
    int k0 = blockIdx.x * 32;   // center dim
    int y0 = blockIdx.y * 32;   // Y dim
    int tx = threadIdx.x & 31;
    int ty = threadIdx.x >> 5;  // 0..7
    #pragma unroll
    for (int i = 0; i < 4; ++i) {
        int k = k0 + ty + i * 8;
        float v = (k < M_CENT) ? w[(size_t)k * Y_DIM + y0 + tx] : 0.f;
        tile[tx][ty + i * 8] = v;     // tile[y_local][k_local]
    }
    __syncthreads();
    #pragma unroll
    for (int i = 0; i < 4; ++i) {
        int yl = ty + i * 8;
        wT[(size_t)(y0 + yl) * M_PAD + k0 + tx] = f2bf(tile[yl][tx]);
    }
}

// ---------------------------------------------------------------------------
// R8 = R7 with ONE change (R7 post-mortem: WRITE_SIZE 480MB / FETCH 764MB =
// ~400MB scratch-spill round-trip; persistent xq[16 VGPR]+zq[4] across
// Phase 1 blew the 128-arch-VGPR budget; dur tied R2's 644 only because the
// counted-vmcnt pipeline gain was eaten by spill traffic):
//  - xq/zq live range SHRUNK TO PHASE 2: loaded right after the Phase-1->2
//    barrier (L2-hot; once per tile; covered by Phase-2 exp work).  Phase-1
//    register pressure now BELOW R6's HW-proven no-spill set.
//  - Everything else byte-identical to R7 (clean A/B):
//    * R2 geometry: BM=64, 4 waves, MSPLIT=8, 1024 blocks, 2 resident/CU
//      (LDS exactly 81920 B, HW-verified).
//    * R6/R7 counted-vmcnt raw-barrier pipeline (T3+T4, HW-verified):
//        barA -> STAGE(next buf, 10 gll16) -> s_waitcnt vmcnt(10) -> barB
//        -> ds_read frags -> 32 MFMA.   vmcnt NEVER drains to 0 in phase 1.
//      p aliases buf1 only; chunk-15 stages next tile's chunk-0 into buf0,
//      landing during Phases 2-3.
//    * v_sqrt_f32 inline; launch_bounds(256,2).
//  Sentinels: WRITE_SIZE ~75MB & FETCH ~440-480MB = spill gone (primary);
//  if WRITE drops but dur ~640 -> stall is elsewhere, ablate phases next.
// ---------------------------------------------------------------------------

#define STAGE(PAR, M0, KBASE) do {                                            \
    _Pragma("unroll")                                                         \
    for (int i_ = 0; i_ < 2; ++i_) {          /* X: 512 16B-chunks */         \
        int lin_ = t + i_ * 256;                                              \
        int row_ = lin_ >> 3, c_ = lin_ & 7;                                  \
        gll16(&lds_all[(PAR) * BUFE + lin_ * 8],                              \
              Xb + (size_t)(row0 + row_) * D_DIM + (KBASE) +                  \
                  ((c_ ^ (row_ & 7)) * 8));                                   \
    }                                                                         \
    _Pragma("unroll")                                                         \
    for (int i_ = 0; i_ < 8; ++i_) {          /* Z: 2048 16B-chunks */        \
        int lin_ = t + i_ * 256;                                              \
        int row_ = lin_ >> 3, c_ = lin_ & 7;                                  \
        gll16(&lds_all[(PAR) * BUFE + ZOFF + lin_ * 8],                       \
              Zb + (size_t)((M0) + row_) * D_DIM + (KBASE) +                  \
                  ((c_ ^ (row_ & 7)) * 8));                                   \
    } } while (0)

// One K-chunk.  PAR literal 0/1.  On entry: [stage(kc)x10] outstanding
// (issued one chunk earlier); buf[PAR^1]'s readers all passed barA.
// vmcnt(10) keeps the 10 JUST-ISSUED ops outstanding and drains everything
// older (stage(kc) + any stray scalar loads) -- robust counting.
#define CHUNK(PAR, M0N, KBN) do {                                             \
    asm volatile("" ::: "memory");                                            \
    __builtin_amdgcn_s_barrier();          /* barA: buf[PAR^1] free */        \
    asm volatile("" ::: "memory");                                            \
    STAGE(PAR ^ 1, M0N, KBN);                                                 \
    __builtin_amdgcn_sched_barrier(0);                                        \
    asm volatile("s_waitcnt vmcnt(10)" ::: "memory"); /* stage(kc) done */    \
    __builtin_amdgcn_s_barrier();          /* barB: everyone's stage done */  \
    asm volatile("" ::: "memory");                                            \
    _Pragma("unroll")                                                         \
    for (int kt_ = 0; kt_ < 2; ++kt_) {                                       \
        const int sw_ = ((kt_ * 4 + quad) ^ cx) * 8;                          \
        bf16x8 a_[4], b_[4];                                                  \
        _Pragma("unroll")                                                     \
        for (int it_ = 0; it_ < 4; ++it_)                                     \
            a_[it_] = *(const bf16x8*)&lds_all[(PAR) * BUFE +                 \
                (it_ * 16 + l16) * BK + sw_];                                 \
        _Pragma("unroll")                                                     \
        for (int jt_ = 0; jt_ < 4; ++jt_)                                     \
            b_[jt_] = *(const bf16x8*)&lds_all[(PAR) * BUFE + ZOFF +          \
                (wave * 64 + jt_ * 16 + l16) * BK + sw_];                     \
        __builtin_amdgcn_s_setprio(1);                                        \
        _Pragma("unroll")                                                     \
        for (int it_ = 0; it_ < 4; ++it_)                                     \
            _Pragma("unroll")                                                 \
            for (int jt_ = 0; jt_ < 4; ++jt_)                                 \
                S[it_ * 4 + jt_] = __builtin_amdgcn_mfma_f32_16x16x32_bf16(   \
                    a_[it_], b_[jt_], S[it_ * 4 + jt_], 0, 0, 0);             \
        __builtin_amdgcn_s_setprio(0);                                        \
    } } while (0)

__global__ void __launch_bounds__(256, 2)
fused_kernel(const unsigned short* __restrict__ Xb,
             const unsigned short* __restrict__ Zb,
             const unsigned short* __restrict__ WbT,
             const float* __restrict__ xsq,
             const float* __restrict__ zsq,
             const int* __restrict__ bwp,
             float* __restrict__ out) {
    __shared__ unsigned short lds_all[2 * BUFE];   // EXACTLY 81920 B

    const int t    = threadIdx.x;
    const int wave = t >> 6;      // 0..3: m-slab (phase1 B, phase3 y-slab)
    const int lane = t & 63;
    const int quad = lane >> 4;
    const int l16  = lane & 15;
    const int cx   = l16 & 7;     // row&7 of every frag row this lane touches

    const int row0 = blockIdx.x * BM;          // R2 known-good mapping
    const int mt0  = blockIdx.y * TILES_PER_SPLIT;
    int mt_end = mt0 + TILES_PER_SPLIT;
    if (mt_end > M_TILES) mt_end = M_TILES;

    // bandwidth: int32 per harness convention (Python int 10); tolerate float bits too
    int bwi = *bwp;
    float bw;
    if (bwi > 0 && bwi < 1000000) bw = (float)bwi;
    else { union { int i; float f; } u; u.i = bwi; bw = u.f; }
    const float inv_bw = 1.0f / bw;

    const f32x4 vzero = {0.f, 0.f, 0.f, 0.f};
    f32x4 Oacc[16];
    #pragma unroll
    for (int i = 0; i < 16; ++i) Oacc[i] = vzero;

    // prologue: stage (tile mt0, chunk 0) -> buf0
    STAGE(0, mt0 * BN, 0);
    __builtin_amdgcn_sched_barrier(0);

    for (int mt = mt0; mt < mt_end; ++mt) {
        const int m0 = mt * BN;
        // last tile of split prefetches itself (valid mem, unused)
        const int m0next = (mt + 1 < mt_end) ? m0 + BN : m0;

        f32x4 S[16];
        #pragma unroll
        for (int i = 0; i < 16; ++i) S[i] = vzero;

        // -------- Phase 1: S[64x256] = X * Z^T over D, counted-vmcnt pipe --
        // chunk kc reads buf[kc&1]; stages kc+1 into buf[(kc+1)&1].
        // kc=15 stages NEXT TILE's chunk 0 into buf0 (disjoint from p),
        // landing during Phases 2-3 -> no drain at tile boundary.
        // NOTE (R8): no xq/zq registers live here -> pressure below R6's
        // HW-proven no-spill configuration.
        #pragma unroll 1
        for (int kc = 0; kc < NCHUNK; kc += 2) {
            const bool last = (kc + 2 == NCHUNK);
            CHUNK(0, m0, (kc + 1) * BK);
            CHUNK(1, last ? m0next : m0, last ? 0 : (kc + 2) * BK);
        }

        // phase1 -> phase2: all buf1 readers done before p overwrites it
        asm volatile("" ::: "memory");
        __builtin_amdgcn_s_barrier();
        asm volatile("" ::: "memory");

        // -------- Phase 2: P = exp(-sqrt(d2)/bw) -> p (bf16) --------
        // xq/zq loaded HERE (L2-hot, once per tile): live range = Phase 2
        // only.  Compiler-inserted waitcnt before first use also sweeps the
        // in-flight buf0 prefetch -- harmless, it was issued a chunk ago.
        f32x4 xq[4];
        #pragma unroll
        for (int it = 0; it < 4; ++it)
            xq[it] = *(const f32x4*)(xsq + row0 + it * 16 + quad * 4);
        float zq[4];
        #pragma unroll
        for (int jt = 0; jt < 4; ++jt)
            zq[jt] = zsq[m0 + wave * 64 + jt * 16 + l16];

        #pragma unroll
        for (int it = 0; it < 4; ++it) {
            #pragma unroll
            for (int jt = 0; jt < 4; ++jt) {
                f32x4 s4 = S[it * 4 + jt];
                const int col = wave * 64 + jt * 16 + l16;
                #pragma unroll
                for (int r = 0; r < 4; ++r) {
                    const int row = it * 16 + quad * 4 + r;   // C-layout
                    float d2 = xq[it][r] + zq[jt] - 2.0f * s4[r];
                    d2 = fmaxf(d2, 0.f);
                    float d;
                    asm("v_sqrt_f32 %0, %1" : "=v"(d) : "v"(d2));
                    float p = __expf(-d * inv_bw);
                    lds_all[POFF + row * LDSP_STRIDE + col] = f2bf(p);
                }
            }
        }
        // P-write -> P-read: LDS-only drain; buf0 prefetch stays in flight
        asm volatile("s_waitcnt lgkmcnt(0)" ::: "memory");
        __builtin_amdgcn_s_barrier();
        asm volatile("" ::: "memory");

        // -------- Phase 3: O += P[64x256] * Wtile[256x256] --------
        #pragma unroll
        for (int ks = 0; ks < 8; ++ks) {
            const int koff = ks * 32 + quad * 8;
            bf16x8 a[4], b[4];
            #pragma unroll
            for (int rt = 0; rt < 4; ++rt)
                a[rt] = *(const bf16x8*)&lds_all[POFF +
                    (rt * 16 + l16) * LDSP_STRIDE + koff];
            #pragma unroll
            for (int ct = 0; ct < 4; ++ct) {
                const int y = wave * 64 + ct * 16 + l16;
                b[ct] = *(const bf16x8*)(WbT + (size_t)y * M_PAD + m0 + koff);
            }
            __builtin_amdgcn_s_setprio(1);
            #pragma unroll
            for (int rt = 0; rt < 4; ++rt)
                #pragma unroll
                for (int ct = 0; ct < 4; ++ct)
                    Oacc[rt * 4 + ct] = __builtin_amdgcn_mfma_f32_16x16x32_bf16(
                        a[rt], b[ct], Oacc[rt * 4 + ct], 0, 0, 0);
            __builtin_amdgcn_s_setprio(0);
        }
        // next tile's CHUNK(0) barA separates these p reads from the next
        // stage writes into buf1 (p ds_reads are lgkm-drained pre-MFMA).
    }

    // drain the dangling last-tile prefetch before LDS is released
    asm volatile("s_waitcnt vmcnt(0)" ::: "memory");

    // -------- epilogue: accumulate M-splits via device-scope fp32 atomics ----
    #pragma unroll
    for (int rt = 0; rt < 4; ++rt) {
        #pragma unroll
        for (int ct = 0; ct < 4; ++ct) {
            f32x4 v = Oacc[rt * 4 + ct];
            const int y = wave * 64 + ct * 16 + l16;
            #pragma unroll
            for (int r = 0; r < 4; ++r) {
                const int row = row0 + rt * 16 + quad * 4 + r;
                atomicAdd(&out[(size_t)row * Y_DIM + y], v[r]);
            }
        }
    }
}

extern "C" void kernel_launch(void* const* d_in, const int* in_sizes, int n_in,
                              void* d_out, int out_size, void* d_ws, size_t ws_size,
                              hipStream_t stream) {
    const float* X = (const float*)d_in[0];
    const float* Z = (const float*)d_in[1];
    const float* W = (const float*)d_in[2];
    const int*  bw = (const int*)d_in[3];
    float* out = (float*)d_out;

    char* ws = (char*)d_ws;
    size_t off = 0;
    unsigned short* Xb  = (unsigned short*)(ws + off); off += (size_t)N_ROWS * D_DIM * 2;
    unsigned short* Zb  = (unsigned short*)(ws + off); off += (size_t)M_PAD * D_DIM * 2;
    unsigned short* WbT = (unsigned short*)(ws + off); off += (size_t)Y_DIM * M_PAD * 2;
    float* xsq = (float*)(ws + off); off += (size_t)N_ROWS * 4;
    float* zsq = (float*)(ws + off); off += (size_t)M_PAD * 4;
    // total ws use: ~68.7 MB

    hipMemsetAsync(d_out, 0, (size_t)out_size * sizeof(float), stream);
    cast_rows_kernel<<<N_ROWS, 256, 0, stream>>>(X, Xb, xsq, N_ROWS);
    cast_rows_kernel<<<M_PAD, 256, 0, stream>>>(Z, Zb, zsq, M_CENT);
    cast_wT_kernel<<<dim3(M_PAD / 32, Y_DIM / 32), 256, 0, stream>>>(W, WbT);
    fused_kernel<<<dim3(N_ROWS / BM, MSPLIT), 256, 0, stream>>>(
        Xb, Zb, WbT, xsq, zsq, bw, out);
}